// Round 5
// baseline (133.061 us; speedup 1.0000x reference)
//
#include <hip/hip_runtime.h>
#include <stdint.h>

#define BB 4
#define CC 64
#define HH 192
#define WW 192
#define HWN (HH*WW)            // 36864
#define KH 4
#define KW 16
#define PW (WW/KW)             // 12
#define MP ((HH/KH)*(WW/KW))   // 576
#define NT 128                 // n-tile per block
#define MT 64                  // m-tile per iteration
#define MITER (MP/MT)          // 9
#define SCALE_W 65536.0f
#define INV_SCALE (1.0f/65536.0f)

typedef _Float16 half8 __attribute__((ext_vector_type(8)));
typedef _Float16 half4 __attribute__((ext_vector_type(4)));
typedef float floatx4 __attribute__((ext_vector_type(4)));

// async global->LDS, 16B per lane; LDS dest = uniform base + lane*16 (HW rule)
static __device__ __forceinline__ void gload16(const void* g, void* l) {
  __builtin_amdgcn_global_load_lds((const __attribute__((address_space(1))) void*)g,
                                   (__attribute__((address_space(3))) void*)l, 16, 0, 0);
}
#define WAITCNT_VM(N) asm volatile("s_waitcnt vmcnt(" #N ")" ::: "memory")
#define WAITCNT_LGKM0 asm volatile("s_waitcnt lgkmcnt(0)" ::: "memory")

// kptF fragment order (GEMM1 B-operand, cols permuted m=l15*4+mf):
//   chunk = (mi*4+mf)*2+ks per batch; f16 idx = chunk*512 + lane*8 + e
//   value = Kp[b][m=mi*64+(lane&15)*4+mf][c=ks*32+(lane>>4)*8+e]
// wqF fragment order (GEMM2 A-operand):
//   chunk = (mi*4+cf)*2+ks ; value = W'[b][c=cf*16+(lane&15)][m=mi*64+ks*32+(lane>>4)*8+e]

// ---------------- pooling: kptF (f16 frag-order) and Vp (f32, [b][c][m]) ---
__global__ __launch_bounds__(256) void pool_kernel(
    const float* __restrict__ Kin, const float* __restrict__ Vin,
    _Float16* __restrict__ kptF, float* __restrict__ vp) {
  int t = blockIdx.x * 256 + threadIdx.x;
  const int total = BB * CC * MP;
  bool isV = t >= total;
  int idx = isV ? t - total : t;
  int m = idx % MP;
  int c = (idx / MP) % CC;
  int b = idx / (MP * CC);
  int mh = m / PW, mw = m % PW;
  const float* src = (isV ? Vin : Kin) + (((b * CC + c) * HH + mh * KH) * WW + mw * KW);
  float s = 0.f;
#pragma unroll
  for (int r = 0; r < KH; ++r) {
    const float4* row = (const float4*)(src + r * WW);
#pragma unroll
    for (int j = 0; j < KW / 4; ++j) {
      float4 v = row[j];
      s += v.x + v.y + v.z + v.w;
    }
  }
  s *= (1.0f / (KH * KW));
  if (isV) {
    vp[(b * CC + c) * MP + m] = s;
  } else {
    int mi = m >> 6, mloc = m & 63, l15 = mloc >> 2, mf = mloc & 3;
    int ks = c >> 5, lhi = (c >> 3) & 3, e = c & 7;
    int lane = lhi * 16 + l15;
    kptF[(((((b * MITER + mi) * 4 + mf) * 2 + ks)) * 64 + lane) * 8 + e] = (_Float16)s;
  }
}

// ---------------- pass A: colsum[b][m] = sum_n exp(scores[b][n][m]) --------
// LDS-staged B tiles (3-buf rotation, 2 ahead); fire-forget LDS atomics.
__global__ __launch_bounds__(256) void colsum_kernel(
    const float* __restrict__ Q, const _Float16* __restrict__ kptF,
    float* __restrict__ colsum) {
  __shared__ float cs[MP];
  __shared__ char stg[3 * 8192];
  int b = blockIdx.y;
  int n0 = blockIdx.x * NT;
  int tid = threadIdx.x;
  int wv = tid >> 6;
  int lane = tid & 63;
  int l15 = lane & 15, lhi = lane >> 4;

  for (int i = tid; i < MP; i += 256) cs[i] = 0.f;

  const float* Qb = Q + b * CC * HWN;
  int nrow = n0 + wv * 32 + l15;
  half8 afrag[2][2];
#pragma unroll
  for (int nf = 0; nf < 2; ++nf)
#pragma unroll
    for (int ks = 0; ks < 2; ++ks) {
      int cbase = ks * 32 + lhi * 8;
      int n = nrow + nf * 16;
#pragma unroll
      for (int e = 0; e < 8; ++e)
        afrag[nf][ks][e] = (_Float16)Qb[(cbase + e) * HWN + n];
    }

  const _Float16* kb = kptF + b * MITER * 8 * 512;
  // prologue: stage tiles 0,1 (8 chunks of 1KB each; 2 chunks per wave)
  {
    int q0 = wv * 2;
#pragma unroll
    for (int j = 0; j < 2; ++j)
      gload16(kb + 0 * 4096 + (q0 + j) * 512 + lane * 8, stg + 0 * 8192 + (q0 + j) * 1024);
#pragma unroll
    for (int j = 0; j < 2; ++j)
      gload16(kb + 1 * 4096 + (q0 + j) * 512 + lane * 8, stg + 1 * 8192 + (q0 + j) * 1024);
  }
  WAITCNT_LGKM0;  // cs zero-init visible
  WAITCNT_VM(2);  // afrag + tile0 done (tile1's 2 may fly)
  __builtin_amdgcn_sched_barrier(0);
  __builtin_amdgcn_s_barrier();

  floatx4 zero = {0.f, 0.f, 0.f, 0.f};
#pragma unroll
  for (int mi = 0; mi < MITER; ++mi) {
    half8 bfr[4][2];
#pragma unroll
    for (int mf = 0; mf < 4; ++mf)
#pragma unroll
      for (int ks = 0; ks < 2; ++ks)
        bfr[mf][ks] = *(const half8*)(stg + (mi % 3) * 8192 + (mf * 2 + ks) * 1024 + lane * 16);
    if (mi + 2 < MITER) {
      int q0 = wv * 2;
#pragma unroll
      for (int j = 0; j < 2; ++j)
        gload16(kb + (mi + 2) * 4096 + (q0 + j) * 512 + lane * 8,
                stg + ((mi + 2) % 3) * 8192 + (q0 + j) * 1024);
    }
    floatx4 sacc[2][4];
#pragma unroll
    for (int nf = 0; nf < 2; ++nf)
#pragma unroll
      for (int mf = 0; mf < 4; ++mf) sacc[nf][mf] = zero;
    __builtin_amdgcn_s_setprio(1);
#pragma unroll
    for (int ks = 0; ks < 2; ++ks)
#pragma unroll
      for (int nf = 0; nf < 2; ++nf)
#pragma unroll
        for (int mf = 0; mf < 4; ++mf)
          sacc[nf][mf] = __builtin_amdgcn_mfma_f32_16x16x32_f16(
              afrag[nf][ks], bfr[mf][ks], sacc[nf][mf], 0, 0, 0);
    __builtin_amdgcn_s_setprio(0);
    // per-lane 8-sum + fire-and-forget LDS atomic (no shfl waits)
#pragma unroll
    for (int mf = 0; mf < 4; ++mf) {
      float s = 0.f;
#pragma unroll
      for (int nf = 0; nf < 2; ++nf)
#pragma unroll
        for (int r = 0; r < 4; ++r)
          s += __expf(sacc[nf][mf][r]);
      atomicAdd(&cs[mi * MT + l15 * 4 + mf], s);
    }
    if (mi < MITER - 1) {
      if (mi + 2 < MITER) { WAITCNT_VM(2); } else { WAITCNT_VM(0); }
      __builtin_amdgcn_sched_barrier(0);
      __builtin_amdgcn_s_barrier();
    }
  }
  __syncthreads();
  for (int i = tid; i < MP; i += 256) atomicAdd(&colsum[b * MP + i], cs[i]);
}

// ---------------- W' = Vp/colsum * 2^16 (f16, frag-order) ------------------
__global__ __launch_bounds__(256) void wprep_kernel(
    const float* __restrict__ vp, const float* __restrict__ colsum,
    _Float16* __restrict__ wqF) {
  int t = blockIdx.x * 256 + threadIdx.x;
  int m = t % MP;
  int c = (t / MP) % CC;
  int b = t / (CC * MP);
  float w = vp[t] / colsum[b * MP + m] * SCALE_W;
  int cf = c >> 4, l15 = c & 15;
  int mi = m >> 6, mloc = m & 63;
  int ks = mloc >> 5, lhi = (mloc >> 3) & 3, e = mloc & 7;
  int lane = lhi * 16 + l15;
  wqF[((((b * MITER + mi) * 4 + cf) * 2 + ks) * 64 + lane) * 8 + e] = (_Float16)w;
}

// ---------------- pass B: out[b][c][n] = sum_m W'[c][m]*E[n][m] * 2^-16 ----
// LDS-staged kptF+wqF tiles (3-buf rotation, 16KB each, 2 ahead, counted vmcnt);
// 2-deep compute pipeline: body(mi) = GEMM1(mi) || GEMM2(mi-1); E dbl-buffered.
__global__ __launch_bounds__(256) void attn_main_kernel(
    const float* __restrict__ Q, const _Float16* __restrict__ kptF,
    const _Float16* __restrict__ wqF, float* __restrict__ out) {
  __shared__ char lds[3 * 16384 + 4 * 8192];  // 48KB stage + 32KB E
  char* stg = lds;
  int b = blockIdx.y;
  int n0 = blockIdx.x * NT;
  int tid = threadIdx.x;
  int wv = tid >> 6;
  int lane = tid & 63;
  int l15 = lane & 15, lhi = lane >> 4;
  char* eb0 = lds + 49152 + wv * 8192;
  char* eb1 = eb0 + 4096;

  const float* Qb = Q + b * CC * HWN;
  int nrow = n0 + wv * 32 + l15;
  half8 afrag[2][2];
#pragma unroll
  for (int nf = 0; nf < 2; ++nf)
#pragma unroll
    for (int ks = 0; ks < 2; ++ks) {
      int cbase = ks * 32 + lhi * 8;
      int n = nrow + nf * 16;
#pragma unroll
      for (int e = 0; e < 8; ++e)
        afrag[nf][ks][e] = (_Float16)Qb[(cbase + e) * HWN + n];
    }

  floatx4 zero = {0.f, 0.f, 0.f, 0.f};
  floatx4 oacc[4][2];
#pragma unroll
  for (int cf = 0; cf < 4; ++cf)
#pragma unroll
    for (int nf = 0; nf < 2; ++nf) oacc[cf][nf] = zero;

  const _Float16* kb = kptF + b * MITER * 8 * 512;
  const _Float16* wb = wqF + b * MITER * 8 * 512;

  // stage tile t -> slot s: 16 chunks of 1KB (8 kptF + 8 wqF), 4 per wave
#define STAGE_T(t, s)                                                          \
  {                                                                            \
    int q0_ = wv * 4;                                                          \
    _Pragma("unroll") for (int j_ = 0; j_ < 4; ++j_) {                         \
      int q_ = q0_ + j_;                                                       \
      const _Float16* srcp_ = (q_ < 8 ? kb + (t)*4096 + q_ * 512               \
                                      : wb + (t)*4096 + (q_ - 8) * 512) +      \
                              lane * 8;                                        \
      gload16(srcp_, stg + (s)*16384 + q_ * 1024);                             \
    }                                                                          \
  }

  STAGE_T(0, 0);
  STAGE_T(1, 1);
  WAITCNT_VM(4);  // afrag + tile0 done (tile1's 4 may fly)
  __builtin_amdgcn_sched_barrier(0);
  __builtin_amdgcn_s_barrier();

#pragma unroll
  for (int mi = 0; mi < MITER; ++mi) {
    const int sc = mi % 3;            // slot holding tile mi
    const int sp = (mi + 2) % 3;      // == (mi-1)%3 : prev tile slot / next stage target
    char* ebR = ((mi - 1) & 1) ? eb1 : eb0;
    char* ebW = (mi & 1) ? eb1 : eb0;

    // ds reads: current B tile, prev W tile, prev E fragments
    half8 bfr[4][2];
#pragma unroll
    for (int mf = 0; mf < 4; ++mf)
#pragma unroll
      for (int ks = 0; ks < 2; ++ks)
        bfr[mf][ks] = *(const half8*)(stg + sc * 16384 + (mf * 2 + ks) * 1024 + lane * 16);
    half8 wfr[4][2];
    half8 ef[2][2];
    if (mi >= 1) {
#pragma unroll
      for (int cf = 0; cf < 4; ++cf)
#pragma unroll
        for (int ks = 0; ks < 2; ++ks)
          wfr[cf][ks] = *(const half8*)(stg + sp * 16384 + 8192 + (cf * 2 + ks) * 1024 + lane * 16);
#pragma unroll
      for (int nf = 0; nf < 2; ++nf)
#pragma unroll
        for (int ks = 0; ks < 2; ++ks) {
          int nl = nf * 16 + l15;
          int slot = (ks * 4 + lhi) ^ (nl & 7);
          ef[nf][ks] = *(const half8*)(ebR + nl * 128 + (slot << 4));
        }
    }

    if (mi >= 1 && mi + 2 < MITER) {
      // about to overwrite slot sp which we just read (wfr): drain LDS reads first
      WAITCNT_LGKM0;
      __builtin_amdgcn_sched_barrier(0);
    }
    if (mi + 2 < MITER) STAGE_T(mi + 2, sp);

    // GEMM1(mi)
    floatx4 sacc[2][4];
#pragma unroll
    for (int nf = 0; nf < 2; ++nf)
#pragma unroll
      for (int mf = 0; mf < 4; ++mf) sacc[nf][mf] = zero;
    __builtin_amdgcn_s_setprio(1);
#pragma unroll
    for (int ks = 0; ks < 2; ++ks)
#pragma unroll
      for (int nf = 0; nf < 2; ++nf)
#pragma unroll
        for (int mf = 0; mf < 4; ++mf)
          sacc[nf][mf] = __builtin_amdgcn_mfma_f32_16x16x32_f16(
              afrag[nf][ks], bfr[mf][ks], sacc[nf][mf], 0, 0, 0);
    // GEMM2(mi-1)
    if (mi >= 1) {
#pragma unroll
      for (int ks = 0; ks < 2; ++ks)
#pragma unroll
        for (int cf = 0; cf < 4; ++cf)
#pragma unroll
          for (int nf = 0; nf < 2; ++nf)
            oacc[cf][nf] = __builtin_amdgcn_mfma_f32_16x16x32_f16(
                wfr[cf][ks], ef[nf][ks], oacc[cf][nf], 0, 0, 0);
    }
    __builtin_amdgcn_s_setprio(0);

    // exp -> f16 -> packed swizzled per-wave LDS (8x ds_write_b64)
#pragma unroll
    for (int nf = 0; nf < 2; ++nf)
#pragma unroll
      for (int r = 0; r < 4; ++r) {
        int nl = nf * 16 + lhi * 4 + r;
        half4 h;
#pragma unroll
        for (int mf = 0; mf < 4; ++mf) h[mf] = (_Float16)__expf(sacc[nf][mf][r]);
        int byte = nl * 128 + ((((l15 >> 1) ^ (nl & 7))) << 4) + ((l15 & 1) << 3);
        *(half4*)(ebW + byte) = h;
      }

    if (mi < MITER - 1) {
      if (mi + 2 < MITER) { WAITCNT_VM(4); } else { WAITCNT_VM(0); }
      __builtin_amdgcn_sched_barrier(0);
      __builtin_amdgcn_s_barrier();
    }
  }

  // epilogue: GEMM2(8): W tile 8 in slot 2, E(8) in eb0 (8&1==0)
  {
    half8 wfr[4][2];
#pragma unroll
    for (int cf = 0; cf < 4; ++cf)
#pragma unroll
      for (int ks = 0; ks < 2; ++ks)
        wfr[cf][ks] = *(const half8*)(stg + 2 * 16384 + 8192 + (cf * 2 + ks) * 1024 + lane * 16);
    half8 ef[2][2];
#pragma unroll
    for (int nf = 0; nf < 2; ++nf)
#pragma unroll
      for (int ks = 0; ks < 2; ++ks) {
        int nl = nf * 16 + l15;
        int slot = (ks * 4 + lhi) ^ (nl & 7);
        ef[nf][ks] = *(const half8*)(eb0 + nl * 128 + (slot << 4));
      }
    __builtin_amdgcn_s_setprio(1);
#pragma unroll
    for (int ks = 0; ks < 2; ++ks)
#pragma unroll
      for (int cf = 0; cf < 4; ++cf)
#pragma unroll
        for (int nf = 0; nf < 2; ++nf)
          oacc[cf][nf] = __builtin_amdgcn_mfma_f32_16x16x32_f16(
              wfr[cf][ks], ef[nf][ks], oacc[cf][nf], 0, 0, 0);
    __builtin_amdgcn_s_setprio(0);
  }

  float* ob = out + b * CC * HWN;
#pragma unroll
  for (int cf = 0; cf < 4; ++cf)
#pragma unroll
    for (int nf = 0; nf < 2; ++nf)
#pragma unroll
      for (int r = 0; r < 4; ++r) {
        int c = cf * 16 + lhi * 4 + r;
        int n = n0 + wv * 32 + nf * 16 + l15;
        ob[c * HWN + n] = oacc[cf][nf][r] * INV_SCALE;
      }
}

extern "C" void kernel_launch(void* const* d_in, const int* in_sizes, int n_in,
                              void* d_out, int out_size, void* d_ws, size_t ws_size,
                              hipStream_t stream) {
  const float* K = (const float*)d_in[0];
  const float* Q = (const float*)d_in[1];
  const float* V = (const float*)d_in[2];
  float* out = (float*)d_out;
  char* ws = (char*)d_ws;
  _Float16* kptF  = (_Float16*)(ws);                          // 294912 B
  float*    vp    = (float*)(ws + 294912);                    // 589824 B
  _Float16* wqF   = (_Float16*)(ws + 294912 + 589824);        // 294912 B
  float*    colsum = (float*)(ws + 294912 + 589824 + 294912); // 9216 B

  hipMemsetAsync(colsum, 0, BB * MP * sizeof(float), stream);
  pool_kernel<<<(2 * BB * CC * MP) / 256, 256, 0, stream>>>(K, V, kptF, vp);
  colsum_kernel<<<dim3(HWN / NT, BB), 256, 0, stream>>>(Q, kptF, colsum);
  wprep_kernel<<<(BB * CC * MP) / 256, 256, 0, stream>>>(vp, colsum, wqF);
  attn_main_kernel<<<dim3(HWN / NT, BB), 256, 0, stream>>>(Q, kptF, wqF, out);
}

// Round 6
// 126.624 us; speedup vs baseline: 1.0508x; 1.0508x over previous
//
#include <hip/hip_runtime.h>

#define BB 4
#define CC 64
#define HH 192
#define WW 192
#define HWN (HH*WW)            // 36864
#define KH 4
#define KW 16
#define PW (WW/KW)             // 12
#define MP ((HH/KH)*(WW/KW))   // 576
#define NT 128                 // n-tile per block
#define MT 64                  // m-tile per iteration
#define MITER (MP/MT)          // 9
#define SCALE_W 65536.0f
#define INV_SCALE (1.0f/65536.0f)

typedef _Float16 half8 __attribute__((ext_vector_type(8)));
typedef _Float16 half4 __attribute__((ext_vector_type(4)));
typedef float floatx4 __attribute__((ext_vector_type(4)));

// kptF fragment order (GEMM1 B-operand, cols permuted m=l15*4+mf):
//   chunk = (mi*4+mf)*2+ks per batch; f16 idx = chunk*512 + lane*8 + e
//   value = Kp[b][m=mi*64+(lane&15)*4+mf][c=ks*32+(lane>>4)*8+e]
// wqF fragment order (GEMM2 A-operand):
//   chunk = (mi*4+cf)*2+ks ; value = W'[b][c=cf*16+(lane&15)][m=mi*64+ks*32+(lane>>4)*8+e]

// ---------------- pooling: kptF (f16 frag-order) and Vp (f32, [b][c][m]) ---
__global__ __launch_bounds__(256) void pool_kernel(
    const float* __restrict__ Kin, const float* __restrict__ Vin,
    _Float16* __restrict__ kptF, float* __restrict__ vp) {
  int t = blockIdx.x * 256 + threadIdx.x;
  const int total = BB * CC * MP;
  bool isV = t >= total;
  int idx = isV ? t - total : t;
  int m = idx % MP;
  int c = (idx / MP) % CC;
  int b = idx / (MP * CC);
  int mh = m / PW, mw = m % PW;
  const float* src = (isV ? Vin : Kin) + (((b * CC + c) * HH + mh * KH) * WW + mw * KW);
  float s = 0.f;
#pragma unroll
  for (int r = 0; r < KH; ++r) {
    const float4* row = (const float4*)(src + r * WW);
#pragma unroll
    for (int j = 0; j < KW / 4; ++j) {
      float4 v = row[j];
      s += v.x + v.y + v.z + v.w;
    }
  }
  s *= (1.0f / (KH * KW));
  if (isV) {
    vp[(b * CC + c) * MP + m] = s;
  } else {
    int mi = m >> 6, mloc = m & 63, l15 = mloc >> 2, mf = mloc & 3;
    int ks = c >> 5, lhi = (c >> 3) & 3, e = c & 7;
    int lane = lhi * 16 + l15;
    kptF[(((((b * MITER + mi) * 4 + mf) * 2 + ks)) * 64 + lane) * 8 + e] = (_Float16)s;
  }
}

// ---------------- pass A: colsum[b][m] = sum_n exp(scores[b][n][m]) --------
// Register 2-deep pipeline (no barriers, no staging); frag-order coalesced
// B loads; per-iter reduce = fire-and-forget ds_add_f32 (no shfl chains).
__global__ __launch_bounds__(256) void colsum_kernel(
    const float* __restrict__ Q, const _Float16* __restrict__ kptF,
    float* __restrict__ colsum) {
  __shared__ float cs[MP];
  int b = blockIdx.y;
  int n0 = blockIdx.x * NT;
  int tid = threadIdx.x;
  int wv = tid >> 6;
  int lane = tid & 63;
  int l15 = lane & 15, lhi = lane >> 4;

  for (int i = tid; i < MP; i += 256) cs[i] = 0.f;
  __syncthreads();

  // A-fragments: rows = n (16/frag), k = c. Q is [c][n] -> 64B-coalesced per e.
  const float* Qb = Q + b * CC * HWN;
  int nrow = n0 + wv * 32 + l15;
  half8 afrag[2][2];
#pragma unroll
  for (int nf = 0; nf < 2; ++nf)
#pragma unroll
    for (int ks = 0; ks < 2; ++ks) {
      int cbase = ks * 32 + lhi * 8;
      int n = nrow + nf * 16;
#pragma unroll
      for (int e = 0; e < 8; ++e)
        afrag[nf][ks][e] = (_Float16)Qb[(cbase + e) * HWN + n];
    }

  const _Float16* kb = kptF + b * MITER * 8 * 512;
  floatx4 zero = {0.f, 0.f, 0.f, 0.f};

  half8 bb[2][4][2];        // double-banked B fragments (frag-order, coalesced)
  floatx4 sacc[2][2][4];    // double-banked score acc [parity][nf][mf]

#pragma unroll
  for (int mf = 0; mf < 4; ++mf)
#pragma unroll
    for (int ks = 0; ks < 2; ++ks)
      bb[0][mf][ks] = *(const half8*)(kb + ((0 * 4 + mf) * 2 + ks) * 512 + lane * 8);
#pragma unroll
  for (int mf = 0; mf < 4; ++mf)
#pragma unroll
    for (int ks = 0; ks < 2; ++ks)
      bb[1][mf][ks] = *(const half8*)(kb + ((1 * 4 + mf) * 2 + ks) * 512 + lane * 8);

  // body 0: GEMM1(0) only
#pragma unroll
  for (int nf = 0; nf < 2; ++nf)
#pragma unroll
    for (int mf = 0; mf < 4; ++mf) sacc[0][nf][mf] = zero;
  __builtin_amdgcn_s_setprio(1);
#pragma unroll
  for (int ks = 0; ks < 2; ++ks)
#pragma unroll
    for (int nf = 0; nf < 2; ++nf)
#pragma unroll
      for (int mf = 0; mf < 4; ++mf)
        sacc[0][nf][mf] = __builtin_amdgcn_mfma_f32_16x16x32_f16(
            afrag[nf][ks], bb[0][mf][ks], sacc[0][nf][mf], 0, 0, 0);
  __builtin_amdgcn_s_setprio(0);

#pragma unroll
  for (int mi = 1; mi <= 8; ++mi) {
    int cur = mi & 1, prv = (mi - 1) & 1;
    if (mi + 1 <= 8) {
#pragma unroll
      for (int mf = 0; mf < 4; ++mf)
#pragma unroll
        for (int ks = 0; ks < 2; ++ks)
          bb[(mi + 1) & 1][mf][ks] =
              *(const half8*)(kb + (((mi + 1) * 4 + mf) * 2 + ks) * 512 + lane * 8);
    }
#pragma unroll
    for (int nf = 0; nf < 2; ++nf)
#pragma unroll
      for (int mf = 0; mf < 4; ++mf) sacc[cur][nf][mf] = zero;
    __builtin_amdgcn_s_setprio(1);
#pragma unroll
    for (int ks = 0; ks < 2; ++ks)
#pragma unroll
      for (int nf = 0; nf < 2; ++nf)
#pragma unroll
        for (int mf = 0; mf < 4; ++mf)
          sacc[cur][nf][mf] = __builtin_amdgcn_mfma_f32_16x16x32_f16(
              afrag[nf][ks], bb[cur][mf][ks], sacc[cur][nf][mf], 0, 0, 0);
    __builtin_amdgcn_s_setprio(0);
    // reduce(mi-1): all 64 lanes, fire-and-forget ds_add (no dependent chain)
#pragma unroll
    for (int mf = 0; mf < 4; ++mf) {
      float s = 0.f;
#pragma unroll
      for (int nf = 0; nf < 2; ++nf)
#pragma unroll
        for (int r = 0; r < 4; ++r)
          s += __expf(sacc[prv][nf][mf][r]);
      atomicAdd(&cs[(mi - 1) * MT + l15 * 4 + mf], s);
    }
  }
  // reduce(8) (lives in sacc[0])
#pragma unroll
  for (int mf = 0; mf < 4; ++mf) {
    float s = 0.f;
#pragma unroll
    for (int nf = 0; nf < 2; ++nf)
#pragma unroll
      for (int r = 0; r < 4; ++r)
        s += __expf(sacc[0][nf][mf][r]);
    atomicAdd(&cs[8 * MT + l15 * 4 + mf], s);
  }
  __syncthreads();
  for (int i = tid; i < MP; i += 256) atomicAdd(&colsum[b * MP + i], cs[i]);
}

// ---------------- W' = Vp/colsum * 2^16 (f16, frag-order) ------------------
__global__ __launch_bounds__(256) void wprep_kernel(
    const float* __restrict__ vp, const float* __restrict__ colsum,
    _Float16* __restrict__ wqF) {
  int t = blockIdx.x * 256 + threadIdx.x;
  int m = t % MP;
  int c = (t / MP) % CC;
  int b = t / (CC * MP);
  float w = vp[t] / colsum[b * MP + m] * SCALE_W;
  int cf = c >> 4, l15 = c & 15;
  int mi = m >> 6, mloc = m & 63;
  int ks = mloc >> 5, lhi = (mloc >> 3) & 3, e = mloc & 7;
  int lane = lhi * 16 + l15;
  wqF[((((b * MITER + mi) * 4 + cf) * 2 + ks) * 64 + lane) * 8 + e] = (_Float16)w;
}

// ---------------- pass B: out[b][c][n] = sum_m W'[c][m]*E[n][m] * 2^-16 ----
// Register 2-deep pipeline: body(mi) = GEMM1(mi) || GEMM2(mi-1); E double-
// buffered per-wave in LDS; frag-order coalesced bb/ww loads; no barriers.
__global__ __launch_bounds__(256) void attn_main_kernel(
    const float* __restrict__ Q, const _Float16* __restrict__ kptF,
    const _Float16* __restrict__ wqF, float* __restrict__ out) {
  __shared__ char elds[4 * 8192];  // 4 waves x 2 bufs x 4KB
  int b = blockIdx.y;
  int n0 = blockIdx.x * NT;
  int tid = threadIdx.x;
  int wv = tid >> 6;
  int lane = tid & 63;
  int l15 = lane & 15, lhi = lane >> 4;
  char* eb0 = elds + wv * 8192;
  char* eb1 = eb0 + 4096;

  const float* Qb = Q + b * CC * HWN;
  int nrow = n0 + wv * 32 + l15;
  half8 afrag[2][2];
#pragma unroll
  for (int nf = 0; nf < 2; ++nf)
#pragma unroll
    for (int ks = 0; ks < 2; ++ks) {
      int cbase = ks * 32 + lhi * 8;
      int n = nrow + nf * 16;
#pragma unroll
      for (int e = 0; e < 8; ++e)
        afrag[nf][ks][e] = (_Float16)Qb[(cbase + e) * HWN + n];
    }

  floatx4 zero = {0.f, 0.f, 0.f, 0.f};
  floatx4 oacc[4][2];
#pragma unroll
  for (int cf = 0; cf < 4; ++cf)
#pragma unroll
    for (int nf = 0; nf < 2; ++nf) oacc[cf][nf] = zero;

  const _Float16* kb = kptF + b * MITER * 8 * 512;
  const _Float16* wb = wqF + b * MITER * 8 * 512;

  half8 bb[2][4][2];  // B fragments (kptF), double-banked
  half8 ww[2][4][2];  // W fragments (wqF), double-banked
  floatx4 sacc[2][4];

  // prologue loads: bfrag(0), wfrag(0) — coalesced 1KB chunks
#pragma unroll
  for (int mf = 0; mf < 4; ++mf)
#pragma unroll
    for (int ks = 0; ks < 2; ++ks)
      bb[0][mf][ks] = *(const half8*)(kb + ((0 * 4 + mf) * 2 + ks) * 512 + lane * 8);
#pragma unroll
  for (int cf = 0; cf < 4; ++cf)
#pragma unroll
    for (int ks = 0; ks < 2; ++ks)
      ww[0][cf][ks] = *(const half8*)(wb + ((0 * 4 + cf) * 2 + ks) * 512 + lane * 8);

  // body 0: prefetch bfrag(1); GEMM1(0); exp-write(0)
#pragma unroll
  for (int mf = 0; mf < 4; ++mf)
#pragma unroll
    for (int ks = 0; ks < 2; ++ks)
      bb[1][mf][ks] = *(const half8*)(kb + ((1 * 4 + mf) * 2 + ks) * 512 + lane * 8);
#pragma unroll
  for (int nf = 0; nf < 2; ++nf)
#pragma unroll
    for (int mf = 0; mf < 4; ++mf) sacc[nf][mf] = zero;
  __builtin_amdgcn_s_setprio(1);
#pragma unroll
  for (int ks = 0; ks < 2; ++ks)
#pragma unroll
    for (int nf = 0; nf < 2; ++nf)
#pragma unroll
      for (int mf = 0; mf < 4; ++mf)
        sacc[nf][mf] = __builtin_amdgcn_mfma_f32_16x16x32_f16(
            afrag[nf][ks], bb[0][mf][ks], sacc[nf][mf], 0, 0, 0);
  __builtin_amdgcn_s_setprio(0);
#pragma unroll
  for (int nf = 0; nf < 2; ++nf)
#pragma unroll
    for (int r = 0; r < 4; ++r) {
      int nl = nf * 16 + lhi * 4 + r;
      half4 h;
#pragma unroll
      for (int mf = 0; mf < 4; ++mf) h[mf] = (_Float16)__expf(sacc[nf][mf][r]);
      int byte = nl * 128 + ((((l15 >> 1) ^ (nl & 7))) << 4) + ((l15 & 1) << 3);
      *(half4*)(eb0 + byte) = h;
    }

  // steady bodies: mi = 1..8
#pragma unroll
  for (int mi = 1; mi <= 8; ++mi) {
    int cur = mi & 1, prv = (mi - 1) & 1;
    char* ebR = prv ? eb1 : eb0;   // read E(mi-1)
    char* ebW = cur ? eb1 : eb0;   // write E(mi)

    // E(mi-1) fragments from LDS (latency hidden under GEMM1)
    half8 ef[2][2];
#pragma unroll
    for (int nf = 0; nf < 2; ++nf)
#pragma unroll
      for (int ks = 0; ks < 2; ++ks) {
        int nl = nf * 16 + l15;
        int slot = (ks * 4 + lhi) ^ (nl & 7);
        ef[nf][ks] = *(const half8*)(ebR + nl * 128 + (slot << 4));
      }

    // prefetch bfrag(mi+1)
    if (mi + 1 <= 8) {
#pragma unroll
      for (int mf = 0; mf < 4; ++mf)
#pragma unroll
        for (int ks = 0; ks < 2; ++ks)
          bb[(mi + 1) & 1][mf][ks] =
              *(const half8*)(kb + (((mi + 1) * 4 + mf) * 2 + ks) * 512 + lane * 8);
    }

    // GEMM1(mi)
#pragma unroll
    for (int nf = 0; nf < 2; ++nf)
#pragma unroll
      for (int mf = 0; mf < 4; ++mf) sacc[nf][mf] = zero;
    __builtin_amdgcn_s_setprio(1);
#pragma unroll
    for (int ks = 0; ks < 2; ++ks)
#pragma unroll
      for (int nf = 0; nf < 2; ++nf)
#pragma unroll
        for (int mf = 0; mf < 4; ++mf)
          sacc[nf][mf] = __builtin_amdgcn_mfma_f32_16x16x32_f16(
              afrag[nf][ks], bb[cur][mf][ks], sacc[nf][mf], 0, 0, 0);

    // GEMM2(mi-1)
#pragma unroll
    for (int ks = 0; ks < 2; ++ks)
#pragma unroll
      for (int cf = 0; cf < 4; ++cf)
#pragma unroll
        for (int nf = 0; nf < 2; ++nf)
          oacc[cf][nf] = __builtin_amdgcn_mfma_f32_16x16x32_f16(
              ww[prv][cf][ks], ef[nf][ks], oacc[cf][nf], 0, 0, 0);
    __builtin_amdgcn_s_setprio(0);

    // load wfrag(mi) into bank cur (its old tile mi-2 is dead)
#pragma unroll
    for (int cf = 0; cf < 4; ++cf)
#pragma unroll
      for (int ks = 0; ks < 2; ++ks)
        ww[cur][cf][ks] = *(const half8*)(wb + ((mi * 4 + cf) * 2 + ks) * 512 + lane * 8);

    // exp-write(mi)
#pragma unroll
    for (int nf = 0; nf < 2; ++nf)
#pragma unroll
      for (int r = 0; r < 4; ++r) {
        int nl = nf * 16 + lhi * 4 + r;
        half4 h;
#pragma unroll
        for (int mf = 0; mf < 4; ++mf) h[mf] = (_Float16)__expf(sacc[nf][mf][r]);
        int byte = nl * 128 + ((((l15 >> 1) ^ (nl & 7))) << 4) + ((l15 & 1) << 3);
        *(half4*)(ebW + byte) = h;
      }
  }

  // epilogue: GEMM2(8) from eb0 (8&1==0), wfrag bank 0 (holds tile 8)
  {
    half8 ef[2][2];
#pragma unroll
    for (int nf = 0; nf < 2; ++nf)
#pragma unroll
      for (int ks = 0; ks < 2; ++ks) {
        int nl = nf * 16 + l15;
        int slot = (ks * 4 + lhi) ^ (nl & 7);
        ef[nf][ks] = *(const half8*)(eb0 + nl * 128 + (slot << 4));
      }
    __builtin_amdgcn_s_setprio(1);
#pragma unroll
    for (int ks = 0; ks < 2; ++ks)
#pragma unroll
      for (int cf = 0; cf < 4; ++cf)
#pragma unroll
        for (int nf = 0; nf < 2; ++nf)
          oacc[cf][nf] = __builtin_amdgcn_mfma_f32_16x16x32_f16(
              ww[0][cf][ks], ef[nf][ks], oacc[cf][nf], 0, 0, 0);
    __builtin_amdgcn_s_setprio(0);
  }

  // ---- store: D rows = c, cols = n -> 64B-coalesced per 16-lane group ----
  float* ob = out + b * CC * HWN;
#pragma unroll
  for (int cf = 0; cf < 4; ++cf)
#pragma unroll
    for (int nf = 0; nf < 2; ++nf)
#pragma unroll
      for (int r = 0; r < 4; ++r) {
        int c = cf * 16 + lhi * 4 + r;
        int n = n0 + wv * 32 + nf * 16 + l15;
        ob[c * HWN + n] = oacc[cf][nf][r] * INV_SCALE;
      }
}

extern "C" void kernel_launch(void* const* d_in, const int* in_sizes, int n_in,
                              void* d_out, int out_size, void* d_ws, size_t ws_size,
                              hipStream_t stream) {
  const float* K = (const float*)d_in[0];
  const float* Q = (const float*)d_in[1];
  const float* V = (const float*)d_in[2];
  float* out = (float*)d_out;
  char* ws = (char*)d_ws;
  _Float16* kptF  = (_Float16*)(ws);                          // 294912 B
  float*    vp    = (float*)(ws + 294912);                    // 589824 B
  _Float16* wqF   = (_Float16*)(ws + 294912 + 589824);        // 294912 B
  float*    colsum = (float*)(ws + 294912 + 589824 + 294912); // 9216 B

  hipMemsetAsync(colsum, 0, BB * MP * sizeof(float), stream);
  pool_kernel<<<(2 * BB * CC * MP) / 256, 256, 0, stream>>>(K, V, kptF, vp);
  colsum_kernel<<<dim3(HWN / NT, BB), 256, 0, stream>>>(Q, kptF, colsum);
  wprep_kernel<<<(BB * CC * MP) / 256, 256, 0, stream>>>(vp, colsum, wqF);
  attn_main_kernel<<<dim3(HWN / NT, BB), 256, 0, stream>>>(Q, kptF, wqF, out);
}

// Round 7
// 126.166 us; speedup vs baseline: 1.0547x; 1.0036x over previous
//
#include <hip/hip_runtime.h>

#define BB 4
#define CC 64
#define HH 192
#define WW 192
#define HWN (HH*WW)            // 36864
#define KH 4
#define KW 16
#define PW (WW/KW)             // 12
#define MP ((HH/KH)*(WW/KW))   // 576
#define MITER (MP/64)          // 9
#define NTILES (HWN/64)        // 576 n-tiles of 64 rows
#define SCALE_W 65536.0f
#define INV_SCALE (1.0f/65536.0f)

typedef _Float16 half8 __attribute__((ext_vector_type(8)));
typedef _Float16 half4 __attribute__((ext_vector_type(4)));
typedef float floatx4 __attribute__((ext_vector_type(4)));

// kptF fragment order (GEMM1 B-operand, cols permuted m=l15*4+mf):
//   chunk = (mi*4+mf)*2+ks per batch; f16 idx = chunk*512 + lane*8 + e
//   value = Kp[b][m=mi*64+(lane&15)*4+mf][c=ks*32+(lane>>4)*8+e]
// wqF fragment order (GEMM2 A-operand):
//   chunk = (mi*4+cf)*2+ks ; value = W'[b][c=cf*16+(lane&15)][m=mi*64+ks*32+(lane>>4)*8+e]

// ---------------- pooling: kptF (f16 frag-order) and Vp (f32, [b][c][m]) ---
__global__ __launch_bounds__(256) void pool_kernel(
    const float* __restrict__ Kin, const float* __restrict__ Vin,
    _Float16* __restrict__ kptF, float* __restrict__ vp) {
  int t = blockIdx.x * 256 + threadIdx.x;
  const int total = BB * CC * MP;
  bool isV = t >= total;
  int idx = isV ? t - total : t;
  int m = idx % MP;
  int c = (idx / MP) % CC;
  int b = idx / (MP * CC);
  int mh = m / PW, mw = m % PW;
  const float* src = (isV ? Vin : Kin) + (((b * CC + c) * HH + mh * KH) * WW + mw * KW);
  float s = 0.f;
#pragma unroll
  for (int r = 0; r < KH; ++r) {
    const float4* row = (const float4*)(src + r * WW);
#pragma unroll
    for (int j = 0; j < KW / 4; ++j) {
      float4 v = row[j];
      s += v.x + v.y + v.z + v.w;
    }
  }
  s *= (1.0f / (KH * KW));
  if (isV) {
    vp[(b * CC + c) * MP + m] = s;
  } else {
    int mi = m >> 6, mloc = m & 63, l15 = mloc >> 2, mf = mloc & 3;
    int ks = c >> 5, lhi = (c >> 3) & 3, e = c & 7;
    int lane = lhi * 16 + l15;
    kptF[(((((b * MITER + mi) * 4 + mf) * 2 + ks)) * 64 + lane) * 8 + e] = (_Float16)s;
  }
}

// -------- pass A1: per-(n-tile) partial colsum. TLP-first: 6912 tiny blocks.
// part[b][nt][m]  (uses d_out as scratch; dead before attn writes out)
__global__ __launch_bounds__(256) void colsum_part_kernel(
    const float* __restrict__ Q, const _Float16* __restrict__ kptF,
    float* __restrict__ part) {
  __shared__ float cs[192];
  int nt = blockIdx.x;       // 0..575 : 64-row n-tile
  int mchunk = blockIdx.y;   // 0..2   : 3 m-tiles each
  int b = blockIdx.z;
  int tid = threadIdx.x;
  int wv = tid >> 6;
  int lane = tid & 63;
  int l15 = lane & 15, lhi = lane >> 4;

  for (int i = tid; i < 192; i += 256) cs[i] = 0.f;
  __syncthreads();

  const float* Qb = Q + b * CC * HWN;
  int n = nt * 64 + wv * 16 + l15;
  half8 afrag[2];
#pragma unroll
  for (int ks = 0; ks < 2; ++ks)
#pragma unroll
    for (int e = 0; e < 8; ++e)
      afrag[ks][e] = (_Float16)Qb[(ks * 32 + lhi * 8 + e) * HWN + n];

  const _Float16* kb = kptF + b * MITER * 8 * 512;
  floatx4 zero = {0.f, 0.f, 0.f, 0.f};

#pragma unroll
  for (int mc = 0; mc < 3; ++mc) {
    int mi = mchunk * 3 + mc;
    half8 bf[4][2];
#pragma unroll
    for (int mf = 0; mf < 4; ++mf)
#pragma unroll
      for (int ks = 0; ks < 2; ++ks)
        bf[mf][ks] = *(const half8*)(kb + ((mi * 4 + mf) * 2 + ks) * 512 + lane * 8);
    floatx4 sacc[4];
#pragma unroll
    for (int mf = 0; mf < 4; ++mf) sacc[mf] = zero;
    __builtin_amdgcn_s_setprio(1);
#pragma unroll
    for (int ks = 0; ks < 2; ++ks)
#pragma unroll
      for (int mf = 0; mf < 4; ++mf)
        sacc[mf] = __builtin_amdgcn_mfma_f32_16x16x32_f16(
            afrag[ks], bf[mf][ks], sacc[mf], 0, 0, 0);
    __builtin_amdgcn_s_setprio(0);
#pragma unroll
    for (int mf = 0; mf < 4; ++mf) {
      float s = 0.f;
#pragma unroll
      for (int r = 0; r < 4; ++r) s += __expf(sacc[mf][r]);
      s += __shfl_xor(s, 16);
      s += __shfl_xor(s, 32);
      if (lane < 16) atomicAdd(&cs[mc * 64 + l15 * 4 + mf], s);  // 4 adds/entry
    }
  }
  __syncthreads();
  float* p = part + (b * NTILES + nt) * MP + mchunk * 192;
  for (int i = tid; i < 192; i += 256) p[i] = cs[i];  // coalesced, no atomics
}

// -------- pass A2: colsum[b][m] = sum_nt part[b][nt][m] ---------------------
__global__ __launch_bounds__(192) void colsum_reduce_kernel(
    const float* __restrict__ part, float* __restrict__ colsum) {
  int b = blockIdx.y;
  int m = blockIdx.x * 192 + threadIdx.x;
  const float* p = part + b * NTILES * MP + m;
  float s0 = 0.f, s1 = 0.f, s2 = 0.f, s3 = 0.f;
#pragma unroll 4
  for (int nt = 0; nt < NTILES; nt += 4) {
    s0 += p[(nt + 0) * MP];
    s1 += p[(nt + 1) * MP];
    s2 += p[(nt + 2) * MP];
    s3 += p[(nt + 3) * MP];
  }
  colsum[b * MP + m] = (s0 + s1) + (s2 + s3);
}

// ---------------- W' = Vp/colsum * 2^16 (f16, frag-order) ------------------
__global__ __launch_bounds__(256) void wprep_kernel(
    const float* __restrict__ vp, const float* __restrict__ colsum,
    _Float16* __restrict__ wqF) {
  int t = blockIdx.x * 256 + threadIdx.x;
  int m = t % MP;
  int c = (t / MP) % CC;
  int b = t / (CC * MP);
  float w = vp[t] / colsum[b * MP + m] * SCALE_W;
  int cf = c >> 4, l15 = c & 15;
  int mi = m >> 6, mloc = m & 63;
  int ks = mloc >> 5, lhi = (mloc >> 3) & 3, e = mloc & 7;
  int lane = lhi * 16 + l15;
  wqF[((((b * MITER + mi) * 4 + cf) * 2 + ks) * 64 + lane) * 8 + e] = (_Float16)w;
}

// ---------------- pass B: out[b][c][n] = sum_m W'[c][m]*E[n][m] * 2^-16 ----
// Wave = 16 n-rows (NT=64/block) -> 2304 blocks, ~9 waves/SIMD demand.
// 2-deep pipeline: body(mi) = GEMM1(mi) || GEMM2(mi-1); per-wave E dbl-buf.
__global__ __launch_bounds__(256) void attn_main_kernel(
    const float* __restrict__ Q, const _Float16* __restrict__ kptF,
    const _Float16* __restrict__ wqF, float* __restrict__ out) {
  __shared__ char elds[4 * 4096];  // 4 waves x 2 bufs x 2KB
  int b = blockIdx.y;
  int n0 = blockIdx.x * 64;
  int tid = threadIdx.x;
  int wv = tid >> 6;
  int lane = tid & 63;
  int l15 = lane & 15, lhi = lane >> 4;
  char* eb0 = elds + wv * 4096;
  char* eb1 = eb0 + 2048;

  const float* Qb = Q + b * CC * HWN;
  int nrow = n0 + wv * 16 + l15;
  half8 afrag[2];
#pragma unroll
  for (int ks = 0; ks < 2; ++ks)
#pragma unroll
    for (int e = 0; e < 8; ++e)
      afrag[ks][e] = (_Float16)Qb[(ks * 32 + lhi * 8 + e) * HWN + nrow];

  floatx4 zero = {0.f, 0.f, 0.f, 0.f};
  floatx4 oacc[4];
#pragma unroll
  for (int cf = 0; cf < 4; ++cf) oacc[cf] = zero;

  const _Float16* kb = kptF + b * MITER * 8 * 512;
  const _Float16* wb = wqF + b * MITER * 8 * 512;

  half8 bb[2][4][2];
  half8 ww[2][4][2];
  floatx4 sacc[4];

  // prologue: bfrag(0), wfrag(0), bfrag(1)
#pragma unroll
  for (int mf = 0; mf < 4; ++mf)
#pragma unroll
    for (int ks = 0; ks < 2; ++ks)
      bb[0][mf][ks] = *(const half8*)(kb + ((0 * 4 + mf) * 2 + ks) * 512 + lane * 8);
#pragma unroll
  for (int cf = 0; cf < 4; ++cf)
#pragma unroll
    for (int ks = 0; ks < 2; ++ks)
      ww[0][cf][ks] = *(const half8*)(wb + ((0 * 4 + cf) * 2 + ks) * 512 + lane * 8);
#pragma unroll
  for (int mf = 0; mf < 4; ++mf)
#pragma unroll
    for (int ks = 0; ks < 2; ++ks)
      bb[1][mf][ks] = *(const half8*)(kb + ((1 * 4 + mf) * 2 + ks) * 512 + lane * 8);

  // body 0: GEMM1(0) + exp-write(0)
#pragma unroll
  for (int mf = 0; mf < 4; ++mf) sacc[mf] = zero;
  __builtin_amdgcn_s_setprio(1);
#pragma unroll
  for (int ks = 0; ks < 2; ++ks)
#pragma unroll
    for (int mf = 0; mf < 4; ++mf)
      sacc[mf] = __builtin_amdgcn_mfma_f32_16x16x32_f16(
          afrag[ks], bb[0][mf][ks], sacc[mf], 0, 0, 0);
  __builtin_amdgcn_s_setprio(0);
#pragma unroll
  for (int r = 0; r < 4; ++r) {
    int nl = lhi * 4 + r;
    half4 h;
#pragma unroll
    for (int mf = 0; mf < 4; ++mf) h[mf] = (_Float16)__expf(sacc[mf][r]);
    int byte = nl * 128 + ((((l15 >> 1) ^ (nl & 7))) << 4) + ((l15 & 1) << 3);
    *(half4*)(eb0 + byte) = h;
  }

  // steady bodies: mi = 1..8
#pragma unroll
  for (int mi = 1; mi <= 8; ++mi) {
    int cur = mi & 1, prv = (mi - 1) & 1;
    char* ebR = prv ? eb1 : eb0;
    char* ebW = cur ? eb1 : eb0;

    half8 ef[2];
#pragma unroll
    for (int ks = 0; ks < 2; ++ks) {
      int nl = l15;
      int slot = (ks * 4 + lhi) ^ (nl & 7);
      ef[ks] = *(const half8*)(ebR + nl * 128 + (slot << 4));
    }

    if (mi + 1 <= 8) {
#pragma unroll
      for (int mf = 0; mf < 4; ++mf)
#pragma unroll
        for (int ks = 0; ks < 2; ++ks)
          bb[(mi + 1) & 1][mf][ks] =
              *(const half8*)(kb + (((mi + 1) * 4 + mf) * 2 + ks) * 512 + lane * 8);
    }

#pragma unroll
    for (int mf = 0; mf < 4; ++mf) sacc[mf] = zero;
    __builtin_amdgcn_s_setprio(1);
#pragma unroll
    for (int ks = 0; ks < 2; ++ks)
#pragma unroll
      for (int mf = 0; mf < 4; ++mf)
        sacc[mf] = __builtin_amdgcn_mfma_f32_16x16x32_f16(
            afrag[ks], bb[cur][mf][ks], sacc[mf], 0, 0, 0);
#pragma unroll
    for (int ks = 0; ks < 2; ++ks)
#pragma unroll
      for (int cf = 0; cf < 4; ++cf)
        oacc[cf] = __builtin_amdgcn_mfma_f32_16x16x32_f16(
            ww[prv][cf][ks], ef[ks], oacc[cf], 0, 0, 0);
    __builtin_amdgcn_s_setprio(0);

#pragma unroll
    for (int cf = 0; cf < 4; ++cf)
#pragma unroll
      for (int ks = 0; ks < 2; ++ks)
        ww[cur][cf][ks] = *(const half8*)(wb + ((mi * 4 + cf) * 2 + ks) * 512 + lane * 8);

#pragma unroll
    for (int r = 0; r < 4; ++r) {
      int nl = lhi * 4 + r;
      half4 h;
#pragma unroll
      for (int mf = 0; mf < 4; ++mf) h[mf] = (_Float16)__expf(sacc[mf][r]);
      int byte = nl * 128 + ((((l15 >> 1) ^ (nl & 7))) << 4) + ((l15 & 1) << 3);
      *(half4*)(ebW + byte) = h;
    }
  }

  // epilogue: GEMM2(8): E(8) in eb0 (8&1==0), W tile 8 in bank 0
  {
    half8 ef[2];
#pragma unroll
    for (int ks = 0; ks < 2; ++ks) {
      int nl = l15;
      int slot = (ks * 4 + lhi) ^ (nl & 7);
      ef[ks] = *(const half8*)(eb0 + nl * 128 + (slot << 4));
    }
    __builtin_amdgcn_s_setprio(1);
#pragma unroll
    for (int ks = 0; ks < 2; ++ks)
#pragma unroll
      for (int cf = 0; cf < 4; ++cf)
        oacc[cf] = __builtin_amdgcn_mfma_f32_16x16x32_f16(
            ww[0][cf][ks], ef[ks], oacc[cf], 0, 0, 0);
    __builtin_amdgcn_s_setprio(0);
  }

  float* ob = out + b * CC * HWN;
#pragma unroll
  for (int cf = 0; cf < 4; ++cf)
#pragma unroll
    for (int r = 0; r < 4; ++r) {
      int c = cf * 16 + lhi * 4 + r;
      ob[c * HWN + n0 + wv * 16 + l15] = oacc[cf][r] * INV_SCALE;
    }
}

extern "C" void kernel_launch(void* const* d_in, const int* in_sizes, int n_in,
                              void* d_out, int out_size, void* d_ws, size_t ws_size,
                              hipStream_t stream) {
  const float* K = (const float*)d_in[0];
  const float* Q = (const float*)d_in[1];
  const float* V = (const float*)d_in[2];
  float* out = (float*)d_out;
  char* ws = (char*)d_ws;
  _Float16* kptF  = (_Float16*)(ws);                          // 294912 B
  float*    vp    = (float*)(ws + 294912);                    // 589824 B
  _Float16* wqF   = (_Float16*)(ws + 294912 + 589824);        // 294912 B
  float*    colsum = (float*)(ws + 294912 + 589824 + 294912); // 9216 B
  float*    part  = out;  // 5.31 MB scratch inside d_out; dead before attn writes

  pool_kernel<<<(2 * BB * CC * MP) / 256, 256, 0, stream>>>(K, V, kptF, vp);
  colsum_part_kernel<<<dim3(NTILES, 3, BB), 256, 0, stream>>>(Q, kptF, part);
  colsum_reduce_kernel<<<dim3(3, BB), 192, 0, stream>>>(part, colsum);
  wprep_kernel<<<(BB * CC * MP) / 256, 256, 0, stream>>>(vp, colsum, wqF);
  attn_main_kernel<<<dim3(NTILES, BB), 256, 0, stream>>>(Q, kptF, wqF, out);
}

// Round 8
// 97.936 us; speedup vs baseline: 1.3587x; 1.2883x over previous
//
#include <hip/hip_runtime.h>
#include <stdint.h>

#define BB 4
#define CC 64
#define HH 192
#define WW 192
#define HWN (HH*WW)            // 36864
#define KH 4
#define KW 16
#define PW (WW/KW)             // 12
#define MP ((HH/KH)*(WW/KW))   // 576
#define MITER (MP/64)          // 9
#define SCALE_W 65536.0f
#define INV_SCALE (1.0f/65536.0f)

typedef _Float16 half8 __attribute__((ext_vector_type(8)));
typedef _Float16 half4 __attribute__((ext_vector_type(4)));
typedef float floatx4 __attribute__((ext_vector_type(4)));

// async global->LDS, 16B per lane; LDS dest = uniform base + lane*16 (HW rule)
static __device__ __forceinline__ void gload16(const void* g, void* l) {
  __builtin_amdgcn_global_load_lds((const __attribute__((address_space(1))) void*)g,
                                   (__attribute__((address_space(3))) void*)l, 16, 0, 0);
}
#define WAITCNT_VM(N) asm volatile("s_waitcnt vmcnt(" #N ")" ::: "memory")
#define WAITCNT_LGKM0 asm volatile("s_waitcnt lgkmcnt(0)" ::: "memory")

// kptF fragment order (GEMM1 B-operand, cols permuted m=l15*4+mf):
//   chunk = (mi*4+mf)*2+ks per batch; f16 idx = chunk*512 + lane*8 + e
//   value = Kp[b][m=mi*64+(lane&15)*4+mf][c=ks*32+(lane>>4)*8+e]
// wqF fragment order (GEMM2 A-operand):
//   chunk = (mi*4+cf)*2+ks ; value = W'[b][c=cf*16+(lane&15)][m=mi*64+ks*32+(lane>>4)*8+e]

// ---------------- pooling: kptF (f16 frag-order) and Vp (f32, [b][c][m]) ---
__global__ __launch_bounds__(256) void pool_kernel(
    const float* __restrict__ Kin, const float* __restrict__ Vin,
    _Float16* __restrict__ kptF, float* __restrict__ vp) {
  int t = blockIdx.x * 256 + threadIdx.x;
  const int total = BB * CC * MP;
  bool isV = t >= total;
  int idx = isV ? t - total : t;
  int m = idx % MP;
  int c = (idx / MP) % CC;
  int b = idx / (MP * CC);
  int mh = m / PW, mw = m % PW;
  const float* src = (isV ? Vin : Kin) + (((b * CC + c) * HH + mh * KH) * WW + mw * KW);
  float s = 0.f;
#pragma unroll
  for (int r = 0; r < KH; ++r) {
    const float4* row = (const float4*)(src + r * WW);
#pragma unroll
    for (int j = 0; j < KW / 4; ++j) {
      float4 v = row[j];
      s += v.x + v.y + v.z + v.w;
    }
  }
  s *= (1.0f / (KH * KW));
  if (isV) {
    vp[(b * CC + c) * MP + m] = s;
  } else {
    int mi = m >> 6, mloc = m & 63, l15 = mloc >> 2, mf = mloc & 3;
    int ks = c >> 5, lhi = (c >> 3) & 3, e = c & 7;
    int lane = lhi * 16 + l15;
    kptF[(((((b * MITER + mi) * 4 + mf) * 2 + ks)) * 64 + lane) * 8 + e] = (_Float16)s;
  }
}

// ---------------- pass A: colsum[b][m] = sum_n exp(scores[b][n][m]) --------
// 8 waves x 32 rows. Entire kptF batch (72KB) staged ONCE into LDS; loop has
// NO barriers. Operand L2 traffic /8 vs per-wave gathering.
__global__ __launch_bounds__(512) void colsum_kernel(
    const float* __restrict__ Q, const _Float16* __restrict__ kptF,
    float* __restrict__ colsum) {
  __shared__ float cs[MP];
  __shared__ char stg[MITER * 8 * 1024];  // 72KB
  int b = blockIdx.y;
  int n0 = blockIdx.x * 256;
  int tid = threadIdx.x;
  int wv = tid >> 6;
  int lane = tid & 63;
  int l15 = lane & 15, lhi = lane >> 4;

  for (int i = tid; i < MP; i += 512) cs[i] = 0.f;

  // stage all 72 chunks (9 per wave)
  const _Float16* kb = kptF + b * MITER * 8 * 512;
#pragma unroll
  for (int j = 0; j < 9; ++j) {
    int q = wv * 9 + j;
    gload16(kb + q * 512 + lane * 8, stg + q * 1024);
  }

  // A-fragments (normal VGPR loads; compiler tracks deps)
  const float* Qb = Q + b * CC * HWN;
  int nrow = n0 + wv * 32 + l15;
  half8 afrag[2][2];
#pragma unroll
  for (int nf = 0; nf < 2; ++nf)
#pragma unroll
    for (int ks = 0; ks < 2; ++ks)
#pragma unroll
      for (int e = 0; e < 8; ++e)
        afrag[nf][ks][e] = (_Float16)Qb[(ks * 32 + lhi * 8 + e) * HWN + nrow + nf * 16];

  __syncthreads();  // drains vmcnt+lgkm then barrier: stage + cs-init visible

  floatx4 zero = {0.f, 0.f, 0.f, 0.f};
#pragma unroll
  for (int mi = 0; mi < MITER; ++mi) {
    half8 bfr[4][2];
#pragma unroll
    for (int mf = 0; mf < 4; ++mf)
#pragma unroll
      for (int ks = 0; ks < 2; ++ks)
        bfr[mf][ks] = *(const half8*)(stg + ((mi * 4 + mf) * 2 + ks) * 1024 + lane * 16);
    floatx4 sacc[2][4];
#pragma unroll
    for (int nf = 0; nf < 2; ++nf)
#pragma unroll
      for (int mf = 0; mf < 4; ++mf) sacc[nf][mf] = zero;
    __builtin_amdgcn_s_setprio(1);
#pragma unroll
    for (int ks = 0; ks < 2; ++ks)
#pragma unroll
      for (int nf = 0; nf < 2; ++nf)
#pragma unroll
        for (int mf = 0; mf < 4; ++mf)
          sacc[nf][mf] = __builtin_amdgcn_mfma_f32_16x16x32_f16(
              afrag[nf][ks], bfr[mf][ks], sacc[nf][mf], 0, 0, 0);
    __builtin_amdgcn_s_setprio(0);
#pragma unroll
    for (int mf = 0; mf < 4; ++mf) {
      float s = 0.f;
#pragma unroll
      for (int nf = 0; nf < 2; ++nf)
#pragma unroll
        for (int r = 0; r < 4; ++r)
          s += __expf(sacc[nf][mf][r]);
      s += __shfl_xor(s, 16);
      s += __shfl_xor(s, 32);
      if (lane < 16) atomicAdd(&cs[mi * 64 + l15 * 4 + mf], s);
    }
  }
  __syncthreads();
  for (int i = tid; i < MP; i += 512) atomicAdd(&colsum[b * MP + i], cs[i]);
}

// ---------------- W' = Vp/colsum * 2^16 (f16, frag-order) ------------------
__global__ __launch_bounds__(256) void wprep_kernel(
    const float* __restrict__ vp, const float* __restrict__ colsum,
    _Float16* __restrict__ wqF) {
  int t = blockIdx.x * 256 + threadIdx.x;
  int m = t % MP;
  int c = (t / MP) % CC;
  int b = t / (CC * MP);
  float w = vp[t] / colsum[b * MP + m] * SCALE_W;
  int cf = c >> 4, l15 = c & 15;
  int mi = m >> 6, mloc = m & 63;
  int ks = mloc >> 5, lhi = (mloc >> 3) & 3, e = mloc & 7;
  int lane = lhi * 16 + l15;
  wqF[((((b * MITER + mi) * 4 + cf) * 2 + ks) * 64 + lane) * 8 + e] = (_Float16)w;
}

// ---------------- pass B: out[b][c][n] = sum_m W'[c][m]*E[n][m] * 2^-16 ----
// 4 waves x 32 rows. 3-slot ring of 16KB tiles (kpt 8KB + wq 8KB) staged by
// global_load_lds, counted vmcnt(4) (never 0 mid-loop), 2 raw barriers/body.
// E single-buffered per wave (read ef(mi-1) at top, overwrite at bottom).
// LDS = 48KB ring + 16KB E = 64KB -> 2 blocks/CU.
__global__ __launch_bounds__(256) void attn_main_kernel(
    const float* __restrict__ Q, const _Float16* __restrict__ kptF,
    const _Float16* __restrict__ wqF, float* __restrict__ out) {
  __shared__ char lds[3 * 16384 + 4 * 4096];  // 64KB exactly
  char* stg = lds;
  int b = blockIdx.y;
  int n0 = blockIdx.x * 128;
  int tid = threadIdx.x;
  int wv = tid >> 6;
  int lane = tid & 63;
  int l15 = lane & 15, lhi = lane >> 4;
  char* eb = lds + 49152 + wv * 4096;

  const _Float16* kb = kptF + b * MITER * 8 * 512;
  const _Float16* wb = wqF + b * MITER * 8 * 512;

  // stage tile tt -> slot ss: 16 chunks of 1KB (8 kpt + 8 wq), 4 per wave
#define STAGE_A(tt, ss)                                                        \
  {                                                                            \
    int q0_ = wv * 4;                                                          \
    _Pragma("unroll") for (int j_ = 0; j_ < 4; ++j_) {                         \
      int q_ = q0_ + j_;                                                       \
      const _Float16* sp_ = (q_ < 8 ? kb + (tt) * 4096 + q_ * 512              \
                                    : wb + (tt) * 4096 + (q_ - 8) * 512) +     \
                            lane * 8;                                          \
      gload16(sp_, stg + (ss) * 16384 + q_ * 1024);                            \
    }                                                                          \
  }

  STAGE_A(0, 0);
  STAGE_A(1, 1);

  const float* Qb = Q + b * CC * HWN;
  int nrow = n0 + wv * 32 + l15;
  half8 afrag[2][2];
#pragma unroll
  for (int nf = 0; nf < 2; ++nf)
#pragma unroll
    for (int ks = 0; ks < 2; ++ks)
#pragma unroll
      for (int e = 0; e < 8; ++e)
        afrag[nf][ks][e] = (_Float16)Qb[(ks * 32 + lhi * 8 + e) * HWN + nrow + nf * 16];

  floatx4 zero = {0.f, 0.f, 0.f, 0.f};
  floatx4 oacc[4][2];
#pragma unroll
  for (int cf = 0; cf < 4; ++cf)
#pragma unroll
    for (int nf = 0; nf < 2; ++nf) oacc[cf][nf] = zero;

  // tile0 staged (vmcnt(4) leaves afrag tail/stage1 in flight; afrag is
  // register-dep-tracked by the compiler separately)
  WAITCNT_VM(4);
  __builtin_amdgcn_sched_barrier(0);
  __builtin_amdgcn_s_barrier();

#pragma unroll
  for (int mi = 0; mi < MITER; ++mi) {
    const int sc = mi % 3;
    const int spv = (mi + 2) % 3;  // slot of tile mi-1; also next stage target

    if (mi >= 1) {
      if (mi <= 7) { WAITCNT_VM(4); } else { WAITCNT_VM(0); }
      __builtin_amdgcn_sched_barrier(0);
      __builtin_amdgcn_s_barrier();  // tile mi resident in every wave
    }

    // ds reads: current kpt tile, prev wq tile, prev E fragments
    half8 bfr[4][2];
#pragma unroll
    for (int mf = 0; mf < 4; ++mf)
#pragma unroll
      for (int ks = 0; ks < 2; ++ks)
        bfr[mf][ks] = *(const half8*)(stg + sc * 16384 + (mf * 2 + ks) * 1024 + lane * 16);
    half8 wfr[4][2];
    half8 ef[2][2];
    if (mi >= 1) {
#pragma unroll
      for (int cf = 0; cf < 4; ++cf)
#pragma unroll
        for (int ks = 0; ks < 2; ++ks)
          wfr[cf][ks] = *(const half8*)(stg + spv * 16384 + 8192 + (cf * 2 + ks) * 1024 + lane * 16);
#pragma unroll
      for (int nf = 0; nf < 2; ++nf)
#pragma unroll
        for (int ks = 0; ks < 2; ++ks) {
          int nl = nf * 16 + l15;
          int slot = (ks * 4 + lhi) ^ (nl & 7);
          ef[nf][ks] = *(const half8*)(eb + nl * 128 + (slot << 4));
        }
    }

    WAITCNT_LGKM0;  // all reads of slot spv (and E) landed in regs
    __builtin_amdgcn_sched_barrier(0);
    __builtin_amdgcn_s_barrier();  // every wave done reading slot spv

    if (mi + 2 < MITER) STAGE_A(mi + 2, spv);

    // GEMM1(mi) + GEMM2(mi-1)
    floatx4 sacc[2][4];
#pragma unroll
    for (int nf = 0; nf < 2; ++nf)
#pragma unroll
      for (int mf = 0; mf < 4; ++mf) sacc[nf][mf] = zero;
    __builtin_amdgcn_s_setprio(1);
#pragma unroll
    for (int ks = 0; ks < 2; ++ks)
#pragma unroll
      for (int nf = 0; nf < 2; ++nf)
#pragma unroll
        for (int mf = 0; mf < 4; ++mf)
          sacc[nf][mf] = __builtin_amdgcn_mfma_f32_16x16x32_f16(
              afrag[nf][ks], bfr[mf][ks], sacc[nf][mf], 0, 0, 0);
    if (mi >= 1) {
#pragma unroll
      for (int ks = 0; ks < 2; ++ks)
#pragma unroll
        for (int cf = 0; cf < 4; ++cf)
#pragma unroll
          for (int nf = 0; nf < 2; ++nf)
            oacc[cf][nf] = __builtin_amdgcn_mfma_f32_16x16x32_f16(
                wfr[cf][ks], ef[nf][ks], oacc[cf][nf], 0, 0, 0);
    }
    __builtin_amdgcn_s_setprio(0);

    // exp -> f16 -> swizzled per-wave E (overwrites; reads already drained)
#pragma unroll
    for (int nf = 0; nf < 2; ++nf)
#pragma unroll
      for (int r = 0; r < 4; ++r) {
        int nl = nf * 16 + lhi * 4 + r;
        half4 h;
#pragma unroll
        for (int mf = 0; mf < 4; ++mf) h[mf] = (_Float16)__expf(sacc[nf][mf][r]);
        int byte = nl * 128 + ((((l15 >> 1) ^ (nl & 7))) << 4) + ((l15 & 1) << 3);
        *(half4*)(eb + byte) = h;
      }
  }

  // epilogue: GEMM2(8): wq tile 8 in slot 2 (intact), E(8) in eb
  {
    half8 wfr[4][2];
#pragma unroll
    for (int cf = 0; cf < 4; ++cf)
#pragma unroll
      for (int ks = 0; ks < 2; ++ks)
        wfr[cf][ks] = *(const half8*)(stg + 2 * 16384 + 8192 + (cf * 2 + ks) * 1024 + lane * 16);
    half8 ef[2][2];
#pragma unroll
    for (int nf = 0; nf < 2; ++nf)
#pragma unroll
      for (int ks = 0; ks < 2; ++ks) {
        int nl = nf * 16 + l15;
        int slot = (ks * 4 + lhi) ^ (nl & 7);
        ef[nf][ks] = *(const half8*)(eb + nl * 128 + (slot << 4));
      }
    __builtin_amdgcn_s_setprio(1);
#pragma unroll
    for (int ks = 0; ks < 2; ++ks)
#pragma unroll
      for (int cf = 0; cf < 4; ++cf)
#pragma unroll
        for (int nf = 0; nf < 2; ++nf)
          oacc[cf][nf] = __builtin_amdgcn_mfma_f32_16x16x32_f16(
              wfr[cf][ks], ef[nf][ks], oacc[cf][nf], 0, 0, 0);
    __builtin_amdgcn_s_setprio(0);
  }

  float* ob = out + b * CC * HWN;
#pragma unroll
  for (int cf = 0; cf < 4; ++cf)
#pragma unroll
    for (int nf = 0; nf < 2; ++nf)
#pragma unroll
      for (int r = 0; r < 4; ++r) {
        int c = cf * 16 + lhi * 4 + r;
        int n = n0 + wv * 32 + nf * 16 + l15;
        ob[c * HWN + n] = oacc[cf][nf][r] * INV_SCALE;
      }
}

extern "C" void kernel_launch(void* const* d_in, const int* in_sizes, int n_in,
                              void* d_out, int out_size, void* d_ws, size_t ws_size,
                              hipStream_t stream) {
  const float* K = (const float*)d_in[0];
  const float* Q = (const float*)d_in[1];
  const float* V = (const float*)d_in[2];
  float* out = (float*)d_out;
  char* ws = (char*)d_ws;
  _Float16* kptF  = (_Float16*)(ws);                          // 294912 B
  float*    vp    = (float*)(ws + 294912);                    // 589824 B
  _Float16* wqF   = (_Float16*)(ws + 294912 + 589824);        // 294912 B
  float*    colsum = (float*)(ws + 294912 + 589824 + 294912); // 9216 B

  hipMemsetAsync(colsum, 0, BB * MP * sizeof(float), stream);
  pool_kernel<<<(2 * BB * CC * MP) / 256, 256, 0, stream>>>(K, V, kptF, vp);
  colsum_kernel<<<dim3(HWN / 256, BB), 512, 0, stream>>>(Q, kptF, colsum);
  wprep_kernel<<<(BB * CC * MP) / 256, 256, 0, stream>>>(vp, colsum, wqF);
  attn_main_kernel<<<dim3(HWN / 128, BB), 256, 0, stream>>>(Q, kptF, wqF, out);
}